// Round 5
// baseline (201.918 us; speedup 1.0000x reference)
//
#include <hip/hip_runtime.h>
#include <math.h>

// Problem constants
#define N_  8
#define C_  256
#define G_  8
#define CG_ 32
#define K_  9
#define H_  64
#define W_  64
#define L_  (H_*W_)      // 4096
#define OM_ 216          // G*K*3
#define OMP_ 256         // padded om row stride

using frag_ab = __attribute__((ext_vector_type(8))) short;   // 8 bf16
using frag_cd = __attribute__((ext_vector_type(4))) float;   // 4 fp32

__device__ __forceinline__ unsigned short f2bf(float f) {    // RNE fp32->bf16
    unsigned int u = __float_as_uint(f);
    u += 0x7FFFu + ((u >> 16) & 1u);
    return (unsigned short)(u >> 16);
}
__device__ __forceinline__ float bflo(unsigned int u) { return __uint_as_float(u << 16); }
__device__ __forceinline__ float bfhi(unsigned int u) { return __uint_as_float(u & 0xFFFF0000u); }

__device__ __forceinline__ void gld16(const void* g, void* l) {
    __builtin_amdgcn_global_load_lds((const __attribute__((address_space(1))) void*)g,
                                     (__attribute__((address_space(3))) void*)l, 16, 0, 0);
}

// ---------------------------------------------------------------------------
// Weight conversion: vp_w/op_w (256x256), om_w (216x256 -> zero-padded 256x256),
// om_b (216 -> padded 256 fp32). grid 256 x 256 threads.
// ---------------------------------------------------------------------------
__global__ __launch_bounds__(256) void cvt_weights(const float* __restrict__ vp_w,
                                                   const float* __restrict__ om_w,
                                                   const float* __restrict__ om_b,
                                                   const float* __restrict__ op_w,
                                                   unsigned short* __restrict__ vp_wb,
                                                   unsigned short* __restrict__ om_wb,
                                                   float* __restrict__ om_bp,
                                                   unsigned short* __restrict__ op_wb) {
    int idx = blockIdx.x * 256 + threadIdx.x;
    if (idx < C_ * C_) {
        vp_wb[idx] = f2bf(vp_w[idx]);
        op_wb[idx] = f2bf(op_w[idx]);
        om_wb[idx] = (idx < OM_ * C_) ? f2bf(om_w[idx]) : (unsigned short)0;
    }
    if (idx < OMP_) om_bp[idx] = (idx < OM_) ? om_b[idx] : 0.f;
}

// ---------------------------------------------------------------------------
// Fused prep: depthwise 3x3 conv + transpose + bf16 convert of BOTH the conv
// output (omb) and the raw x row (xb), single pass over x.
// grid (C/32, H, N), block 256 = (c 0..31) x (xq 0..7).
// ---------------------------------------------------------------------------
__global__ __launch_bounds__(256) void prep_kernel(const float* __restrict__ x,
                                                   const float* __restrict__ w,
                                                   const float* __restrict__ b,
                                                   unsigned short* __restrict__ xb,
                                                   unsigned short* __restrict__ omb) {
    const int n = blockIdx.z, y = blockIdx.y, c0 = blockIdx.x * 32;
    const int tid = threadIdx.x;
    __shared__ float xs[3][32][66];
    __shared__ __align__(16) unsigned short os[2][64][40];  // [0]=x bf16, [1]=conv
    if (tid < 192) {    // zero the x = -1 / 64 halo columns
        int r = tid / 64, c = (tid / 2) % 32, e = tid & 1;
        xs[r][c][e * 65] = 0.f;
    }
    const float* xbase = x + ((size_t)n * C_ + c0) * L_;
    for (int i = tid; i < 3 * 32 * 16; i += 256) {   // 3 rows x 32 ch x 16 float4
        int r = i >> 9, rem = i & 511, c = rem >> 4, x4 = (rem & 15) * 4;
        int yy = y + r - 1;
        float4 v = make_float4(0.f, 0.f, 0.f, 0.f);
        if ((unsigned)yy < (unsigned)H_) v = *(const float4*)(xbase + (size_t)c * L_ + yy * W_ + x4);
        xs[r][c][1 + x4] = v.x; xs[r][c][2 + x4] = v.y;
        xs[r][c][3 + x4] = v.z; xs[r][c][4 + x4] = v.w;
    }
    __syncthreads();

    const int c = tid & 31, x0 = (tid >> 5) * 8;
    float wv[9];
#pragma unroll
    for (int i = 0; i < 9; i++) wv[i] = w[(c0 + c) * 9 + i];
    const float bias = b[c0 + c];
    float o[8];
#pragma unroll
    for (int j = 0; j < 8; j++) o[j] = bias;
#pragma unroll
    for (int r = 0; r < 3; r++) {
        float v[10];
#pragma unroll
        for (int d = 0; d < 10; d++) v[d] = xs[r][c][x0 + d];
#pragma unroll
        for (int j = 0; j < 8; j++)
            o[j] += wv[r * 3] * v[j] + wv[r * 3 + 1] * v[j + 1] + wv[r * 3 + 2] * v[j + 2];
    }
#pragma unroll
    for (int j = 0; j < 8; j++) {
        os[0][x0 + j][c] = f2bf(xs[1][c][1 + x0 + j]);
        os[1][x0 + j][c] = f2bf(o[j]);
    }
    __syncthreads();

    const int l = tid >> 2, c8 = (tid & 3) * 8;
    uint4 va = *(const uint4*)&os[0][l][c8];
    uint4 vc = *(const uint4*)&os[1][l][c8];
    size_t dst = ((size_t)n * L_ + y * W_ + l) * C_ + c0 + c8;
    *(uint4*)(xb + dst) = va;
    *(uint4*)(omb + dst) = vc;
}

// ---------------------------------------------------------------------------
// Merged GEMM1+GEMM2 (blockIdx.z selects): C[i][j] = sum_k A[i][k]*B[j][k]+bias
// z=0: A=xb,  B=vp_w, D=valueb (bf16, stride 256)
// z=1: A=omb, B=om_w, D=omf    (fp32, stride 256)
// Block 256 (4 waves), tile 128x128, BK=32, mfma 16x16x32.
// grid (256, 2, 2) -> 1024 blocks = 4 blocks/CU.
// ---------------------------------------------------------------------------
__global__ __launch_bounds__(256) void gemm12_kernel(const unsigned short* __restrict__ xb,
                                                     const unsigned short* __restrict__ omb,
                                                     const unsigned short* __restrict__ vp_wb,
                                                     const unsigned short* __restrict__ om_wb,
                                                     const float* __restrict__ vp_b,
                                                     const float* __restrict__ om_bp,
                                                     unsigned short* __restrict__ valueb,
                                                     float* __restrict__ omf) {
    __shared__ unsigned short As[128 * 32];
    __shared__ unsigned short Bs[128 * 32];
    const int which = blockIdx.z;
    const unsigned short* A = which ? omb : xb;
    const unsigned short* B = which ? om_wb : vp_wb;
    const float* bias = which ? om_bp : vp_b;
    const int tid = threadIdx.x;
    const long i0 = (long)blockIdx.x * 128;
    const long j0 = (long)blockIdx.y * 128;
    const unsigned short* Ab = A + i0 * C_;
    const unsigned short* Bb = B + j0 * C_;
    const int wave = tid >> 6, lane = tid & 63;
    const int iw = (wave & 1) * 64, jw = (wave >> 1) * 64;
    const int lm = lane & 15, kq = lane >> 4;
    const int srow = tid >> 2, scol = (tid & 3) * 8;

    frag_cd acc[4][4];
#pragma unroll
    for (int a = 0; a < 4; a++)
#pragma unroll
        for (int c = 0; c < 4; c++) acc[a][c] = (frag_cd){0.f, 0.f, 0.f, 0.f};

    for (int k0 = 0; k0 < C_; k0 += 32) {
        const unsigned short* ga0 = Ab + (long)srow * C_ + k0 + scol;
        const unsigned short* gb0 = Bb + (long)srow * C_ + k0 + scol;
        gld16(ga0,            As + tid * 8);
        gld16(ga0 + 64 * C_,  As + 2048 + tid * 8);
        gld16(gb0,            Bs + tid * 8);
        gld16(gb0 + 64 * C_,  Bs + 2048 + tid * 8);
        __syncthreads();
        frag_ab af[4], bfr[4];
#pragma unroll
        for (int mi = 0; mi < 4; mi++)
            af[mi] = *(const frag_ab*)&As[(iw + mi * 16 + lm) * 32 + kq * 8];
#pragma unroll
        for (int ni = 0; ni < 4; ni++)
            bfr[ni] = *(const frag_ab*)&Bs[(jw + ni * 16 + lm) * 32 + kq * 8];
#pragma unroll
        for (int mi = 0; mi < 4; mi++)
#pragma unroll
            for (int ni = 0; ni < 4; ni++)
                acc[mi][ni] = __builtin_amdgcn_mfma_f32_16x16x32_bf16(af[mi], bfr[ni], acc[mi][ni], 0, 0, 0);
        __syncthreads();
    }

    float bv[4];
#pragma unroll
    for (int ni = 0; ni < 4; ni++)
        bv[ni] = bias[(int)(j0 + jw + ni * 16 + lm)];

    const long ibase = i0 + iw + kq * 4;
    const long jbase = j0 + jw + lm;
#pragma unroll
    for (int mi = 0; mi < 4; mi++) {
#pragma unroll
        for (int ni = 0; ni < 4; ni++) {
            long j = jbase + ni * 16;
#pragma unroll
            for (int r = 0; r < 4; r++) {
                long i = ibase + mi * 16 + r;
                float v = acc[mi][ni][r] + bv[ni];
                if (which)
                    omf[i * OMP_ + j] = v;
                else
                    valueb[i * C_ + j] = f2bf(v);
            }
        }
    }
}

// ---------------------------------------------------------------------------
// Fused sampling + output projection. grid (L/64, N), block 256 (4 waves).
// Phase B: 512 (px,g) pairs, 2 per thread, each covering 32 ch: compute
//   bilinear taps, gather bf16 value (4x uint4 per corner), accumulate,
//   write 64x256 bf16 interm tile to LDS with XOR-swizzled 16B slots.
// Phase C: out[q][px-tile] = op_w @ interm^T via MFMA; A-frags direct from
//   global op_w (L2-resident), B-frags conflict-free ds_read_b128.
// ---------------------------------------------------------------------------
__global__ __launch_bounds__(256) void sampleout_kernel(const unsigned short* __restrict__ value,
                                                        const float* __restrict__ om,
                                                        const unsigned short* __restrict__ opw,
                                                        float* __restrict__ out) {
    const int n = blockIdx.y, l0 = blockIdx.x * 64;
    const int tid = threadIdx.x;
    __shared__ __align__(16) unsigned short interm[64 * 256];   // 32 KB

    const size_t vbase = (size_t)n * L_ * C_;
#pragma unroll
    for (int rep = 0; rep < 2; rep++) {
        const int pair = tid + rep * 256;
        const int p = pair >> 3, g = pair & 7;
        const int l = l0 + p, y = l >> 6, xp = l & 63;
        const float* so = om + ((size_t)n * L_ + l) * OMP_ + g * 27;
        const char* vp = (const char*)(value + vbase + g * CG_);
        float acc[32];
#pragma unroll
        for (int c = 0; c < 32; c++) acc[c] = 0.f;
#pragma unroll
        for (int k = 0; k < K_; k++) {
            float offy = so[2 * k], offx = so[2 * k + 1], mk = so[18 + k];
            float py = (float)(y + k / 3 - 1) + offy;
            float px = (float)(xp + k % 3 - 1) + offx;
            float fy = floorf(py), fx = floorf(px);
            float ty = py - fy, tx = px - fx;
            int y0 = (int)fy, x0i = (int)fx;
            int y1 = y0 + 1, x1 = x0i + 1;
            float vy0 = ((unsigned)y0 < (unsigned)H_) ? 1.f : 0.f;
            float vy1 = ((unsigned)y1 < (unsigned)H_) ? 1.f : 0.f;
            float vx0 = ((unsigned)x0i < (unsigned)W_) ? 1.f : 0.f;
            float vx1 = ((unsigned)x1 < (unsigned)W_) ? 1.f : 0.f;
            int cy0 = min(max(y0, 0), H_ - 1), cy1 = min(max(y1, 0), H_ - 1);
            int cx0 = min(max(x0i, 0), W_ - 1), cx1 = min(max(x1, 0), W_ - 1);
            float w00 = mk * (1.f - ty) * (1.f - tx) * vy0 * vx0;
            float w01 = mk * (1.f - ty) * tx         * vy0 * vx1;
            float w10 = mk * ty         * (1.f - tx) * vy1 * vx0;
            float w11 = mk * ty         * tx         * vy1 * vx1;
            unsigned o00 = (unsigned)((cy0 * W_ + cx0) * (C_ * 2));
            unsigned o01 = (unsigned)((cy0 * W_ + cx1) * (C_ * 2));
            unsigned o10 = (unsigned)((cy1 * W_ + cx0) * (C_ * 2));
            unsigned o11 = (unsigned)((cy1 * W_ + cx1) * (C_ * 2));
#define UNP8(U, BOF, WW) { \
            acc[BOF+0] += WW * bflo(U.x); acc[BOF+1] += WW * bfhi(U.x); \
            acc[BOF+2] += WW * bflo(U.y); acc[BOF+3] += WW * bfhi(U.y); \
            acc[BOF+4] += WW * bflo(U.z); acc[BOF+5] += WW * bfhi(U.z); \
            acc[BOF+6] += WW * bflo(U.w); acc[BOF+7] += WW * bfhi(U.w); }
#define CORNER(OFF, WW) { \
            const uint4* cp = (const uint4*)(vp + OFF); \
            uint4 u0 = cp[0], u1 = cp[1], u2 = cp[2], u3 = cp[3]; \
            UNP8(u0, 0, WW) UNP8(u1, 8, WW) UNP8(u2, 16, WW) UNP8(u3, 24, WW) }
            CORNER(o00, w00) CORNER(o01, w01) CORNER(o10, w10) CORNER(o11, w11)
#undef CORNER
#undef UNP8
        }
        // pack 32 ch -> 4 swizzled 16B slots of interm row p
#pragma unroll
        for (int j = 0; j < 4; j++) {
            uint4 pk;
            unsigned short* ps = (unsigned short*)&pk;
#pragma unroll
            for (int e = 0; e < 8; e++) ps[e] = f2bf(acc[j * 8 + e]);
            int phys = (g * 4 + j) ^ (p & 7);
            *(uint4*)&interm[p * 256 + phys * 8] = pk;
        }
    }
    __syncthreads();

    // Phase C: per wave 64q x 64px, 4x4 frags, K=256 in 8 steps
    const int wave = tid >> 6, lane = tid & 63;
    const int lm = lane & 15, kq = lane >> 4;
    const int q0w = wave * 64;
    frag_cd acc2[4][4];
#pragma unroll
    for (int a = 0; a < 4; a++)
#pragma unroll
        for (int c = 0; c < 4; c++) acc2[a][c] = (frag_cd){0.f, 0.f, 0.f, 0.f};

    for (int k0 = 0; k0 < C_; k0 += 32) {
        frag_ab af[4], bfr[4];
#pragma unroll
        for (int mi = 0; mi < 4; mi++)
            af[mi] = *(const frag_ab*)(opw + (size_t)(q0w + mi * 16 + lm) * C_ + k0 + kq * 8);
#pragma unroll
        for (int ni = 0; ni < 4; ni++) {
            int pxr = ni * 16 + lm;
            int phys = (k0 / 8 + kq) ^ (pxr & 7);
            bfr[ni] = *(const frag_ab*)&interm[pxr * 256 + phys * 8];
        }
#pragma unroll
        for (int mi = 0; mi < 4; mi++)
#pragma unroll
            for (int ni = 0; ni < 4; ni++)
                acc2[mi][ni] = __builtin_amdgcn_mfma_f32_16x16x32_bf16(af[mi], bfr[ni], acc2[mi][ni], 0, 0, 0);
    }

    float* ob = out + (size_t)n * C_ * L_ + l0;
#pragma unroll
    for (int mi = 0; mi < 4; mi++) {
#pragma unroll
        for (int ni = 0; ni < 4; ni++) {
            int pxr = ni * 16 + lm;
#pragma unroll
            for (int r = 0; r < 4; r++) {
                int q = q0w + mi * 16 + kq * 4 + r;
                ob[(size_t)q * L_ + pxr] = acc2[mi][ni][r];
            }
        }
    }
}

// ---------------------------------------------------------------------------
// Workspace layout (84,280,320 B total):
//   [0,        16777216)  xb (n,L,C) bf16
//   [16777216, 33554432)  omb (n,L,C) bf16
//   [33554432, 50331648)  valueb (n,L,C) bf16
//   [50331648, 83886080)  omf (n,L,256) fp32
//   [83886080, ...)       vp_wb, om_wb, op_wb bf16 (128KB each), om_bp fp32
// ---------------------------------------------------------------------------
extern "C" void kernel_launch(void* const* d_in, const int* in_sizes, int n_in,
                              void* d_out, int out_size, void* d_ws, size_t ws_size,
                              hipStream_t stream) {
    const float* x    = (const float*)d_in[0];
    const float* dw_w = (const float*)d_in[1];
    const float* dw_b = (const float*)d_in[2];
    const float* om_w = (const float*)d_in[3];
    const float* om_b = (const float*)d_in[4];
    const float* vp_w = (const float*)d_in[5];
    const float* vp_b = (const float*)d_in[6];
    const float* op_w = (const float*)d_in[7];
    float* out = (float*)d_out;

    char* ws = (char*)d_ws;
    unsigned short* xb      = (unsigned short*)(ws);
    unsigned short* omb     = (unsigned short*)(ws + 16777216);
    unsigned short* valueb  = (unsigned short*)(ws + 33554432);
    float*          omf     = (float*)(ws + 50331648);
    unsigned short* vp_wb   = (unsigned short*)(ws + 83886080);
    unsigned short* om_wb   = (unsigned short*)(ws + 84017152);
    unsigned short* op_wb   = (unsigned short*)(ws + 84148224);
    float*          om_bp   = (float*)(ws + 84279296);

    cvt_weights<<<dim3(256), 256, 0, stream>>>(vp_w, om_w, om_b, op_w,
                                               vp_wb, om_wb, om_bp, op_wb);
    // fused depthwise conv + x transpose (single pass over x)
    prep_kernel<<<dim3(C_ / 32, H_, N_), 256, 0, stream>>>(x, dw_w, dw_b, xb, omb);
    // value = xb @ vp_w^T + vp_b  AND  om = omb @ om_w^T + om_b, one dispatch
    gemm12_kernel<<<dim3(256, 2, 2), 256, 0, stream>>>(
        xb, omb, vp_wb, om_wb, vp_b, om_bp, valueb, omf);
    // fused sampling + output projection -> out (NCHW fp32)
    sampleout_kernel<<<dim3(L_ / 64, N_), 256, 0, stream>>>(valueb, omf, op_wb, out);
}

// Round 6
// 174.363 us; speedup vs baseline: 1.1580x; 1.1580x over previous
//
#include <hip/hip_runtime.h>
#include <math.h>

// Problem constants
#define N_  8
#define C_  256
#define G_  8
#define CG_ 32
#define K_  9
#define H_  64
#define W_  64
#define L_  (H_*W_)      // 4096
#define OM_ 216          // G*K*3
#define OMP_ 256         // padded om row stride

using frag_ab = __attribute__((ext_vector_type(8))) short;   // 8 bf16
using frag_cd = __attribute__((ext_vector_type(4))) float;   // 4 fp32

__device__ __forceinline__ unsigned short f2bf(float f) {    // RNE fp32->bf16
    unsigned int u = __float_as_uint(f);
    u += 0x7FFFu + ((u >> 16) & 1u);
    return (unsigned short)(u >> 16);
}
__device__ __forceinline__ float bflo(unsigned int u) { return __uint_as_float(u << 16); }
__device__ __forceinline__ float bfhi(unsigned int u) { return __uint_as_float(u & 0xFFFF0000u); }

__device__ __forceinline__ void gld16(const void* g, void* l) {
    __builtin_amdgcn_global_load_lds((const __attribute__((address_space(1))) void*)g,
                                     (__attribute__((address_space(3))) void*)l, 16, 0, 0);
}

// ---------------------------------------------------------------------------
// Fused prep: depthwise 3x3 conv + transpose + bf16 convert of BOTH the conv
// output (omb) and the raw x row (xb), single pass over x. ALSO converts the
// three weight matrices to bf16 (spread over the 512 blocks with z==0).
// grid (C/32, H, N), block 256 = (c 0..31) x (xq 0..7).
// ---------------------------------------------------------------------------
__global__ __launch_bounds__(256) void prep_kernel(const float* __restrict__ x,
                                                   const float* __restrict__ w,
                                                   const float* __restrict__ b,
                                                   const float* __restrict__ vp_w,
                                                   const float* __restrict__ om_w,
                                                   const float* __restrict__ om_b,
                                                   const float* __restrict__ op_w,
                                                   unsigned short* __restrict__ xb,
                                                   unsigned short* __restrict__ omb,
                                                   unsigned short* __restrict__ vp_wb,
                                                   unsigned short* __restrict__ om_wb,
                                                   float* __restrict__ om_bp,
                                                   unsigned short* __restrict__ op_wb) {
    const int n = blockIdx.z, y = blockIdx.y, c0 = blockIdx.x * 32;
    const int tid = threadIdx.x;
    __shared__ float xs[3][32][66];
    __shared__ __align__(16) unsigned short os[2][64][40];  // [0]=x bf16, [1]=conv
    if (tid < 192) {    // zero the x = -1 / 64 halo columns
        int r = tid / 64, c = (tid / 2) % 32, e = tid & 1;
        xs[r][c][e * 65] = 0.f;
    }
    const float* xbase = x + ((size_t)n * C_ + c0) * L_;
    for (int i = tid; i < 3 * 32 * 16; i += 256) {   // 3 rows x 32 ch x 16 float4
        int r = i >> 9, rem = i & 511, c = rem >> 4, x4 = (rem & 15) * 4;
        int yy = y + r - 1;
        float4 v = make_float4(0.f, 0.f, 0.f, 0.f);
        if ((unsigned)yy < (unsigned)H_) v = *(const float4*)(xbase + (size_t)c * L_ + yy * W_ + x4);
        xs[r][c][1 + x4] = v.x; xs[r][c][2 + x4] = v.y;
        xs[r][c][3 + x4] = v.z; xs[r][c][4 + x4] = v.w;
    }
    __syncthreads();

    const int c = tid & 31, x0 = (tid >> 5) * 8;
    float wv[9];
#pragma unroll
    for (int i = 0; i < 9; i++) wv[i] = w[(c0 + c) * 9 + i];
    const float bias = b[c0 + c];
    float o[8];
#pragma unroll
    for (int j = 0; j < 8; j++) o[j] = bias;
#pragma unroll
    for (int r = 0; r < 3; r++) {
        float v[10];
#pragma unroll
        for (int d = 0; d < 10; d++) v[d] = xs[r][c][x0 + d];
#pragma unroll
        for (int j = 0; j < 8; j++)
            o[j] += wv[r * 3] * v[j] + wv[r * 3 + 1] * v[j + 1] + wv[r * 3 + 2] * v[j + 2];
    }
#pragma unroll
    for (int j = 0; j < 8; j++) {
        os[0][x0 + j][c] = f2bf(xs[1][c][1 + x0 + j]);
        os[1][x0 + j][c] = f2bf(o[j]);
    }
    __syncthreads();

    const int l = tid >> 2, c8 = (tid & 3) * 8;
    uint4 va = *(const uint4*)&os[0][l][c8];
    uint4 vc = *(const uint4*)&os[1][l][c8];
    size_t dst = ((size_t)n * L_ + y * W_ + l) * C_ + c0 + c8;
    *(uint4*)(xb + dst) = va;
    *(uint4*)(omb + dst) = vc;

    // Weight conversion, folded in: blocks with n==0 cover all 65536 indices.
    if (n == 0) {
        int idx = (blockIdx.x + 8 * blockIdx.y) * 256 + tid;   // 0..131071
        if (idx < C_ * C_) {
            vp_wb[idx] = f2bf(vp_w[idx]);
            op_wb[idx] = f2bf(op_w[idx]);
            om_wb[idx] = (idx < OM_ * C_) ? f2bf(om_w[idx]) : (unsigned short)0;
        }
        if (idx < OMP_) om_bp[idx] = (idx < OM_) ? om_b[idx] : 0.f;
    }
}

// ---------------------------------------------------------------------------
// Merged GEMM1+GEMM2 (blockIdx.z selects): C[i][j] = sum_k A[i][k]*B[j][k]+bias
// z=0: A=xb,  B=vp_w, D=valueb (bf16, stride 256)
// z=1: A=omb, B=om_w, D=omf    (fp32, stride 256)
// Block 256 (4 waves), tile 128x128, BK=32, mfma 16x16x32.
// grid (256, 2, 2) -> 1024 blocks = 4 blocks/CU.
// ---------------------------------------------------------------------------
__global__ __launch_bounds__(256) void gemm12_kernel(const unsigned short* __restrict__ xb,
                                                     const unsigned short* __restrict__ omb,
                                                     const unsigned short* __restrict__ vp_wb,
                                                     const unsigned short* __restrict__ om_wb,
                                                     const float* __restrict__ vp_b,
                                                     const float* __restrict__ om_bp,
                                                     unsigned short* __restrict__ valueb,
                                                     float* __restrict__ omf) {
    __shared__ unsigned short As[128 * 32];
    __shared__ unsigned short Bs[128 * 32];
    const int which = blockIdx.z;
    const unsigned short* A = which ? omb : xb;
    const unsigned short* B = which ? om_wb : vp_wb;
    const float* bias = which ? om_bp : vp_b;
    const int tid = threadIdx.x;
    const long i0 = (long)blockIdx.x * 128;
    const long j0 = (long)blockIdx.y * 128;
    const unsigned short* Ab = A + i0 * C_;
    const unsigned short* Bb = B + j0 * C_;
    const int wave = tid >> 6, lane = tid & 63;
    const int iw = (wave & 1) * 64, jw = (wave >> 1) * 64;
    const int lm = lane & 15, kq = lane >> 4;
    const int srow = tid >> 2, scol = (tid & 3) * 8;

    frag_cd acc[4][4];
#pragma unroll
    for (int a = 0; a < 4; a++)
#pragma unroll
        for (int c = 0; c < 4; c++) acc[a][c] = (frag_cd){0.f, 0.f, 0.f, 0.f};

    for (int k0 = 0; k0 < C_; k0 += 32) {
        const unsigned short* ga0 = Ab + (long)srow * C_ + k0 + scol;
        const unsigned short* gb0 = Bb + (long)srow * C_ + k0 + scol;
        gld16(ga0,            As + tid * 8);
        gld16(ga0 + 64 * C_,  As + 2048 + tid * 8);
        gld16(gb0,            Bs + tid * 8);
        gld16(gb0 + 64 * C_,  Bs + 2048 + tid * 8);
        __syncthreads();
        frag_ab af[4], bfr[4];
#pragma unroll
        for (int mi = 0; mi < 4; mi++)
            af[mi] = *(const frag_ab*)&As[(iw + mi * 16 + lm) * 32 + kq * 8];
#pragma unroll
        for (int ni = 0; ni < 4; ni++)
            bfr[ni] = *(const frag_ab*)&Bs[(jw + ni * 16 + lm) * 32 + kq * 8];
#pragma unroll
        for (int mi = 0; mi < 4; mi++)
#pragma unroll
            for (int ni = 0; ni < 4; ni++)
                acc[mi][ni] = __builtin_amdgcn_mfma_f32_16x16x32_bf16(af[mi], bfr[ni], acc[mi][ni], 0, 0, 0);
        __syncthreads();
    }

    float bv[4];
#pragma unroll
    for (int ni = 0; ni < 4; ni++)
        bv[ni] = bias[(int)(j0 + jw + ni * 16 + lm)];

    const long ibase = i0 + iw + kq * 4;
    const long jbase = j0 + jw + lm;
#pragma unroll
    for (int mi = 0; mi < 4; mi++) {
#pragma unroll
        for (int ni = 0; ni < 4; ni++) {
            long j = jbase + ni * 16;
#pragma unroll
            for (int r = 0; r < 4; r++) {
                long i = ibase + mi * 16 + r;
                float v = acc[mi][ni][r] + bv[ni];
                if (which)
                    omf[i * OMP_ + j] = v;
                else
                    valueb[i * C_ + j] = f2bf(v);
            }
        }
    }
}

// ---------------------------------------------------------------------------
// bf16 MFMA GEMM for the output projection: out[n][q][l] = op_w @ interm[n]^T
// A = op_wb (256x256), B = intermb per batch, D fp32 stride L_.
// Block 256 (4 waves), tile 128x128, BK=32. grid (2, 32, N_).
// ---------------------------------------------------------------------------
__global__ __launch_bounds__(256) void gemm3_kernel(const unsigned short* __restrict__ A,
                                                    const unsigned short* __restrict__ B,
                                                    float* __restrict__ Dv) {
    __shared__ unsigned short As[128 * 32];
    __shared__ unsigned short Bs[128 * 32];
    const int tid = threadIdx.x;
    const long i0 = (long)blockIdx.x * 128;
    const long j0 = (long)blockIdx.y * 128;
    const unsigned short* Ab = A + i0 * C_;
    const unsigned short* Bb = B + (long)blockIdx.z * L_ * C_ + j0 * C_;
    const int wave = tid >> 6, lane = tid & 63;
    const int iw = (wave & 1) * 64, jw = (wave >> 1) * 64;
    const int lm = lane & 15, kq = lane >> 4;
    const int srow = tid >> 2, scol = (tid & 3) * 8;

    frag_cd acc[4][4];
#pragma unroll
    for (int a = 0; a < 4; a++)
#pragma unroll
        for (int c = 0; c < 4; c++) acc[a][c] = (frag_cd){0.f, 0.f, 0.f, 0.f};

    for (int k0 = 0; k0 < C_; k0 += 32) {
        const unsigned short* ga0 = Ab + (long)srow * C_ + k0 + scol;
        const unsigned short* gb0 = Bb + (long)srow * C_ + k0 + scol;
        gld16(ga0,            As + tid * 8);
        gld16(ga0 + 64 * C_,  As + 2048 + tid * 8);
        gld16(gb0,            Bs + tid * 8);
        gld16(gb0 + 64 * C_,  Bs + 2048 + tid * 8);
        __syncthreads();
        frag_ab af[4], bfr[4];
#pragma unroll
        for (int mi = 0; mi < 4; mi++)
            af[mi] = *(const frag_ab*)&As[(iw + mi * 16 + lm) * 32 + kq * 8];
#pragma unroll
        for (int ni = 0; ni < 4; ni++)
            bfr[ni] = *(const frag_ab*)&Bs[(jw + ni * 16 + lm) * 32 + kq * 8];
#pragma unroll
        for (int mi = 0; mi < 4; mi++)
#pragma unroll
            for (int ni = 0; ni < 4; ni++)
                acc[mi][ni] = __builtin_amdgcn_mfma_f32_16x16x32_bf16(af[mi], bfr[ni], acc[mi][ni], 0, 0, 0);
        __syncthreads();
    }

    float* Db = Dv + (long)blockIdx.z * C_ * L_;
    const long ibase = i0 + iw + kq * 4;
    const long jbase = j0 + jw + lm;
#pragma unroll
    for (int mi = 0; mi < 4; mi++) {
#pragma unroll
        for (int ni = 0; ni < 4; ni++) {
            long j = jbase + ni * 16;
#pragma unroll
            for (int r = 0; r < 4; r++) {
                long i = ibase + mi * 16 + r;
                Db[i * L_ + j] = acc[mi][ni][r];
            }
        }
    }
}

// ---------------------------------------------------------------------------
// Deformable bilinear sampling, two-phase (R4 structure, 72 VGPR):
//   phase 1: 576 items (64 (pixel,g) pairs x 9 taps) -> mask-premultiplied
//            bilinear weights (float4) + clamped byte offsets (uint4) in LDS.
//   phase 2: thread = (pair, c8): 8 channels via uint4 bf16 gathers.
// grid (L/8, N), block 256.
// ---------------------------------------------------------------------------
__global__ __launch_bounds__(256) void sample_kernel(const unsigned short* __restrict__ value,
                                                     const float* __restrict__ om,
                                                     unsigned short* __restrict__ interm) {
    const int n = blockIdx.y;
    const int l0 = blockIdx.x * 8;
    const int tid = threadIdx.x;

    __shared__ float sOm[8 * OM_];        // 6912 B
    __shared__ float4 wgt[64][9];         // 9216 B
    __shared__ uint4  soff[64][9];        // 9216 B

    const float* omsrc = om + ((size_t)n * L_ + l0) * OMP_;
    for (int i = tid; i < 8 * OM_; i += 256) {
        int pp = i / OM_;
        sOm[i] = omsrc[pp * OMP_ + (i - pp * OM_)];
    }
    __syncthreads();

    for (int it = tid; it < 576; it += 256) {
        int pair = it / 9, k = it - pair * 9;
        int p = pair >> 3, g = pair & 7;
        int l = l0 + p, y = l >> 6, xp2 = l & 63;
        const float* so = &sOm[p * OM_ + g * 27];
        float offy = so[2 * k], offx = so[2 * k + 1], mk = so[18 + k];
        float py = (float)(y + k / 3 - 1) + offy;
        float px = (float)(xp2 + k % 3 - 1) + offx;
        float fy = floorf(py), fx = floorf(px);
        float ty = py - fy, tx = px - fx;
        int y0 = (int)fy, x0i = (int)fx;
        int y1 = y0 + 1, x1 = x0i + 1;
        float vy0 = ((unsigned)y0 < (unsigned)H_) ? 1.f : 0.f;
        float vy1 = ((unsigned)y1 < (unsigned)H_) ? 1.f : 0.f;
        float vx0 = ((unsigned)x0i < (unsigned)W_) ? 1.f : 0.f;
        float vx1 = ((unsigned)x1 < (unsigned)W_) ? 1.f : 0.f;
        int cy0 = min(max(y0, 0), H_ - 1), cy1 = min(max(y1, 0), H_ - 1);
        int cx0 = min(max(x0i, 0), W_ - 1), cx1 = min(max(x1, 0), W_ - 1);
        wgt[pair][k] = make_float4(mk * (1.f - ty) * (1.f - tx) * vy0 * vx0,
                                   mk * (1.f - ty) * tx         * vy0 * vx1,
                                   mk * ty         * (1.f - tx) * vy1 * vx0,
                                   mk * ty         * tx         * vy1 * vx1);
        soff[pair][k] = make_uint4((unsigned)((cy0 * W_ + cx0) << 9),
                                   (unsigned)((cy0 * W_ + cx1) << 9),
                                   (unsigned)((cy1 * W_ + cx0) << 9),
                                   (unsigned)((cy1 * W_ + cx1) << 9));
    }
    __syncthreads();

    const int pair = tid >> 2, p = pair >> 3, g = pair & 7, c8 = (tid & 3) * 8;
    const char* vb = (const char*)(value + (size_t)n * L_ * C_ + g * CG_ + c8);
    float acc[8] = {0.f, 0.f, 0.f, 0.f, 0.f, 0.f, 0.f, 0.f};
#pragma unroll
    for (int k = 0; k < K_; k++) {
        float4 wk = wgt[pair][k];
        uint4  ok = soff[pair][k];
        const uint4 v00 = *(const uint4*)(vb + ok.x);
        const uint4 v01 = *(const uint4*)(vb + ok.y);
        const uint4 v10 = *(const uint4*)(vb + ok.z);
        const uint4 v11 = *(const uint4*)(vb + ok.w);
#define ACC8(V, WW) { \
        acc[0] += WW * bflo(V.x); acc[1] += WW * bfhi(V.x); \
        acc[2] += WW * bflo(V.y); acc[3] += WW * bfhi(V.y); \
        acc[4] += WW * bflo(V.z); acc[5] += WW * bfhi(V.z); \
        acc[6] += WW * bflo(V.w); acc[7] += WW * bfhi(V.w); }
        ACC8(v00, wk.x) ACC8(v01, wk.y) ACC8(v10, wk.z) ACC8(v11, wk.w)
#undef ACC8
    }
    uint4 pk;
    unsigned short* pp2 = (unsigned short*)&pk;
#pragma unroll
    for (int i = 0; i < 8; i++) pp2[i] = f2bf(acc[i]);
    *(uint4*)(interm + ((size_t)n * L_ + l0 + p) * C_ + g * CG_ + c8) = pk;
}

// ---------------------------------------------------------------------------
// Workspace layout (84,280,320 B total):
//   [0,        16777216)  xb (n,L,C) bf16  -> reused as intermb after GEMM1
//   [16777216, 33554432)  omb (n,L,C) bf16
//   [33554432, 50331648)  valueb (n,L,C) bf16
//   [50331648, 83886080)  omf (n,L,256) fp32
//   [83886080, ...)       vp_wb, om_wb, op_wb bf16 (128KB each), om_bp fp32
// ---------------------------------------------------------------------------
extern "C" void kernel_launch(void* const* d_in, const int* in_sizes, int n_in,
                              void* d_out, int out_size, void* d_ws, size_t ws_size,
                              hipStream_t stream) {
    const float* x    = (const float*)d_in[0];
    const float* dw_w = (const float*)d_in[1];
    const float* dw_b = (const float*)d_in[2];
    const float* om_w = (const float*)d_in[3];
    const float* om_b = (const float*)d_in[4];
    const float* vp_w = (const float*)d_in[5];
    const float* vp_b = (const float*)d_in[6];
    const float* op_w = (const float*)d_in[7];
    float* out = (float*)d_out;

    char* ws = (char*)d_ws;
    unsigned short* xb      = (unsigned short*)(ws);                 // also intermb
    unsigned short* omb     = (unsigned short*)(ws + 16777216);
    unsigned short* valueb  = (unsigned short*)(ws + 33554432);
    float*          omf     = (float*)(ws + 50331648);
    unsigned short* vp_wb   = (unsigned short*)(ws + 83886080);
    unsigned short* om_wb   = (unsigned short*)(ws + 84017152);
    unsigned short* op_wb   = (unsigned short*)(ws + 84148224);
    float*          om_bp   = (float*)(ws + 84279296);
    unsigned short* intermb = xb;

    // 1) fused depthwise conv + x transpose + weight conversion
    prep_kernel<<<dim3(C_ / 32, H_, N_), 256, 0, stream>>>(
        x, dw_w, dw_b, vp_w, om_w, om_b, op_w,
        xb, omb, vp_wb, om_wb, om_bp, op_wb);
    // 2) value = xb @ vp_w^T + vp_b  AND  om = omb @ om_w^T + om_b
    gemm12_kernel<<<dim3(256, 2, 2), 256, 0, stream>>>(
        xb, omb, vp_wb, om_wb, vp_b, om_bp, valueb, omf);
    // 3) sampling -> intermb (reuses xb buffer; xb fully consumed by GEMM1)
    sample_kernel<<<dim3(L_ / 8, N_), 256, 0, stream>>>(valueb, omf, intermb);
    // 4) out[n][q][l] = op_w @ intermb[n]^T  (fp32, directly NCHW)
    gemm3_kernel<<<dim3(2, 32, N_), 256, 0, stream>>>(op_wb, intermb, out);
}

// Round 7
// 168.732 us; speedup vs baseline: 1.1967x; 1.0334x over previous
//
#include <hip/hip_runtime.h>
#include <math.h>

// Problem constants
#define N_  8
#define C_  256
#define G_  8
#define CG_ 32
#define K_  9
#define H_  64
#define W_  64
#define L_  (H_*W_)      // 4096
#define OM_ 216          // G*K*3
#define OMP_ 256         // padded om row stride

using frag_ab = __attribute__((ext_vector_type(8))) short;   // 8 bf16
using frag_cd = __attribute__((ext_vector_type(4))) float;   // 4 fp32

__device__ __forceinline__ unsigned short f2bf(float f) {    // RNE fp32->bf16
    unsigned int u = __float_as_uint(f);
    u += 0x7FFFu + ((u >> 16) & 1u);
    return (unsigned short)(u >> 16);
}
__device__ __forceinline__ float bflo(unsigned int u) { return __uint_as_float(u << 16); }
__device__ __forceinline__ float bfhi(unsigned int u) { return __uint_as_float(u & 0xFFFF0000u); }

__device__ __forceinline__ void gld16(const void* g, void* l) {
    __builtin_amdgcn_global_load_lds((const __attribute__((address_space(1))) void*)g,
                                     (__attribute__((address_space(3))) void*)l, 16, 0, 0);
}

// ---------------------------------------------------------------------------
// Fused prep: depthwise 3x3 conv + transpose + bf16 convert of BOTH the conv
// output (omb) and the raw x row (xb), single pass over x. ALSO converts the
// three weight matrices to bf16 (blocks with n==0).
// grid (C/32, H, N), block 256.
// ---------------------------------------------------------------------------
__global__ __launch_bounds__(256) void prep_kernel(const float* __restrict__ x,
                                                   const float* __restrict__ w,
                                                   const float* __restrict__ b,
                                                   const float* __restrict__ vp_w,
                                                   const float* __restrict__ om_w,
                                                   const float* __restrict__ om_b,
                                                   const float* __restrict__ op_w,
                                                   unsigned short* __restrict__ xb,
                                                   unsigned short* __restrict__ omb,
                                                   unsigned short* __restrict__ vp_wb,
                                                   unsigned short* __restrict__ om_wb,
                                                   float* __restrict__ om_bp,
                                                   unsigned short* __restrict__ op_wb) {
    const int n = blockIdx.z, y = blockIdx.y, c0 = blockIdx.x * 32;
    const int tid = threadIdx.x;
    __shared__ float xs[3][32][66];
    __shared__ __align__(16) unsigned short os[2][64][40];  // [0]=x bf16, [1]=conv
    if (tid < 192) {    // zero the x = -1 / 64 halo columns
        int r = tid / 64, c = (tid / 2) % 32, e = tid & 1;
        xs[r][c][e * 65] = 0.f;
    }
    const float* xbase = x + ((size_t)n * C_ + c0) * L_;
    for (int i = tid; i < 3 * 32 * 16; i += 256) {   // 3 rows x 32 ch x 16 float4
        int r = i >> 9, rem = i & 511, c = rem >> 4, x4 = (rem & 15) * 4;
        int yy = y + r - 1;
        float4 v = make_float4(0.f, 0.f, 0.f, 0.f);
        if ((unsigned)yy < (unsigned)H_) v = *(const float4*)(xbase + (size_t)c * L_ + yy * W_ + x4);
        xs[r][c][1 + x4] = v.x; xs[r][c][2 + x4] = v.y;
        xs[r][c][3 + x4] = v.z; xs[r][c][4 + x4] = v.w;
    }
    __syncthreads();

    const int c = tid & 31, x0 = (tid >> 5) * 8;
    float wv[9];
#pragma unroll
    for (int i = 0; i < 9; i++) wv[i] = w[(c0 + c) * 9 + i];
    const float bias = b[c0 + c];
    float o[8];
#pragma unroll
    for (int j = 0; j < 8; j++) o[j] = bias;
#pragma unroll
    for (int r = 0; r < 3; r++) {
        float v[10];
#pragma unroll
        for (int d = 0; d < 10; d++) v[d] = xs[r][c][x0 + d];
#pragma unroll
        for (int j = 0; j < 8; j++)
            o[j] += wv[r * 3] * v[j] + wv[r * 3 + 1] * v[j + 1] + wv[r * 3 + 2] * v[j + 2];
    }
#pragma unroll
    for (int j = 0; j < 8; j++) {
        os[0][x0 + j][c] = f2bf(xs[1][c][1 + x0 + j]);
        os[1][x0 + j][c] = f2bf(o[j]);
    }
    __syncthreads();

    const int l = tid >> 2, c8 = (tid & 3) * 8;
    uint4 va = *(const uint4*)&os[0][l][c8];
    uint4 vc = *(const uint4*)&os[1][l][c8];
    size_t dst = ((size_t)n * L_ + y * W_ + l) * C_ + c0 + c8;
    *(uint4*)(xb + dst) = va;
    *(uint4*)(omb + dst) = vc;

    // Weight conversion, folded in: blocks with n==0 cover all indices.
    if (n == 0) {
        int idx = (blockIdx.x + 8 * blockIdx.y) * 256 + tid;   // 0..131071
        if (idx < C_ * C_) {
            vp_wb[idx] = f2bf(vp_w[idx]);
            op_wb[idx] = f2bf(op_w[idx]);
            om_wb[idx] = (idx < OM_ * C_) ? f2bf(om_w[idx]) : (unsigned short)0;
        }
        if (idx < OMP_) om_bp[idx] = (idx < OM_) ? om_b[idx] : 0.f;
    }
}

// ---------------------------------------------------------------------------
// Merged GEMM1+GEMM2 (blockIdx.z selects): C[i][j] = sum_k A[i][k]*B[j][k]+bias
// z=0: A=xb,  B=vp_w, D=valueb (bf16, stride 256)
// z=1: A=omb, B=om_w, D=omf    (fp32, stride 256)
// Block 256 (4 waves), tile 128x128, BK=32, mfma 16x16x32. grid (256,2,2).
// ---------------------------------------------------------------------------
__global__ __launch_bounds__(256) void gemm12_kernel(const unsigned short* __restrict__ xb,
                                                     const unsigned short* __restrict__ omb,
                                                     const unsigned short* __restrict__ vp_wb,
                                                     const unsigned short* __restrict__ om_wb,
                                                     const float* __restrict__ vp_b,
                                                     const float* __restrict__ om_bp,
                                                     unsigned short* __restrict__ valueb,
                                                     float* __restrict__ omf) {
    __shared__ unsigned short As[128 * 32];
    __shared__ unsigned short Bs[128 * 32];
    const int which = blockIdx.z;
    const unsigned short* A = which ? omb : xb;
    const unsigned short* B = which ? om_wb : vp_wb;
    const float* bias = which ? om_bp : vp_b;
    const int tid = threadIdx.x;
    const long i0 = (long)blockIdx.x * 128;
    const long j0 = (long)blockIdx.y * 128;
    const unsigned short* Ab = A + i0 * C_;
    const unsigned short* Bb = B + j0 * C_;
    const int wave = tid >> 6, lane = tid & 63;
    const int iw = (wave & 1) * 64, jw = (wave >> 1) * 64;
    const int lm = lane & 15, kq = lane >> 4;
    const int srow = tid >> 2, scol = (tid & 3) * 8;

    frag_cd acc[4][4];
#pragma unroll
    for (int a = 0; a < 4; a++)
#pragma unroll
        for (int c = 0; c < 4; c++) acc[a][c] = (frag_cd){0.f, 0.f, 0.f, 0.f};

    for (int k0 = 0; k0 < C_; k0 += 32) {
        const unsigned short* ga0 = Ab + (long)srow * C_ + k0 + scol;
        const unsigned short* gb0 = Bb + (long)srow * C_ + k0 + scol;
        gld16(ga0,            As + tid * 8);
        gld16(ga0 + 64 * C_,  As + 2048 + tid * 8);
        gld16(gb0,            Bs + tid * 8);
        gld16(gb0 + 64 * C_,  Bs + 2048 + tid * 8);
        __syncthreads();
        frag_ab af[4], bfr[4];
#pragma unroll
        for (int mi = 0; mi < 4; mi++)
            af[mi] = *(const frag_ab*)&As[(iw + mi * 16 + lm) * 32 + kq * 8];
#pragma unroll
        for (int ni = 0; ni < 4; ni++)
            bfr[ni] = *(const frag_ab*)&Bs[(jw + ni * 16 + lm) * 32 + kq * 8];
#pragma unroll
        for (int mi = 0; mi < 4; mi++)
#pragma unroll
            for (int ni = 0; ni < 4; ni++)
                acc[mi][ni] = __builtin_amdgcn_mfma_f32_16x16x32_bf16(af[mi], bfr[ni], acc[mi][ni], 0, 0, 0);
        __syncthreads();
    }

    float bv[4];
#pragma unroll
    for (int ni = 0; ni < 4; ni++)
        bv[ni] = bias[(int)(j0 + jw + ni * 16 + lm)];

    const long ibase = i0 + iw + kq * 4;
    const long jbase = j0 + jw + lm;
#pragma unroll
    for (int mi = 0; mi < 4; mi++) {
#pragma unroll
        for (int ni = 0; ni < 4; ni++) {
            long j = jbase + ni * 16;
#pragma unroll
            for (int r = 0; r < 4; r++) {
                long i = ibase + mi * 16 + r;
                float v = acc[mi][ni][r] + bv[ni];
                if (which)
                    omf[i * OMP_ + j] = v;
                else
                    valueb[i * C_ + j] = f2bf(v);
            }
        }
    }
}

// ---------------------------------------------------------------------------
// Fused sampling + output projection, round 2 (fixes R5's failure modes).
// grid (L/64, N), block 256, __launch_bounds__(256,3) -> VGPR cap ~170.
// Phase B: 8 chunks of 64 (px,g) pairs; per chunk:
//   two-phase tap precompute (576 items -> wgt/soff LDS, om read from global),
//   then 4 threads/pair x 8 ch gathers (acc[8], R4's proven 72-VGPR shape).
//   Interm tile -> LDS with swizzle phys = slot ^ (px&7), slot = tid&31:
//   write banks are a permutation (conflict-free), reads 2-way (free, m136).
// Phase C: out[q][px] = op_w @ interm^T; 4 waves x (64q x 64px), K=256;
//   A-frags from global op_w (L2-resident), B-frags swizzled ds_read_b128.
// LDS 51.2 KB -> 3 blocks/CU; gather phase overlaps other blocks' MFMA (m114).
// ---------------------------------------------------------------------------
__global__ __launch_bounds__(256, 3) void samplegemm_kernel(const unsigned short* __restrict__ value,
                                                            const float* __restrict__ om,
                                                            const unsigned short* __restrict__ opw,
                                                            float* __restrict__ out) {
    const int n = blockIdx.y, l0 = blockIdx.x * 64;
    const int tid = threadIdx.x;
    __shared__ __align__(16) unsigned short interm[64 * 256];   // 32 KB, swizzled
    __shared__ float4 wgt[64][9];                               // 9.2 KB
    __shared__ uint4  soff[64][9];                              // 9.2 KB

    const char* vbase = (const char*)(value + (size_t)n * L_ * C_);
    const int lp = tid >> 2;            // pair-within-chunk 0..63
    const int g = lp & 7;
    const int c8i = tid & 3;
    const int slot = tid & 31;          // = g*4 + c8i
    const char* vb = vbase + (size_t)(g * CG_ + c8i * 8) * 2;

    for (int rep = 0; rep < 8; rep++) {
        __syncthreads();   // wgt/soff safe to overwrite (prev chunk consumed)
        // --- tap precompute for this chunk's 64 pairs ---
        for (int it = tid; it < 576; it += 256) {
            int pl = it / 9, k = it - pl * 9;
            int p = rep * 8 + (pl >> 3), gg = pl & 7;
            int l = l0 + p, y = l >> 6, xp2 = l & 63;
            const float* so = om + ((size_t)n * L_ + l) * OMP_ + gg * 27;
            float offy = so[2 * k], offx = so[2 * k + 1], mk = so[18 + k];
            float py = (float)(y + k / 3 - 1) + offy;
            float px = (float)(xp2 + k % 3 - 1) + offx;
            float fy = floorf(py), fx = floorf(px);
            float ty = py - fy, tx = px - fx;
            int y0 = (int)fy, x0i = (int)fx;
            int y1 = y0 + 1, x1 = x0i + 1;
            float vy0 = ((unsigned)y0 < (unsigned)H_) ? 1.f : 0.f;
            float vy1 = ((unsigned)y1 < (unsigned)H_) ? 1.f : 0.f;
            float vx0 = ((unsigned)x0i < (unsigned)W_) ? 1.f : 0.f;
            float vx1 = ((unsigned)x1 < (unsigned)W_) ? 1.f : 0.f;
            int cy0 = min(max(y0, 0), H_ - 1), cy1 = min(max(y1, 0), H_ - 1);
            int cx0 = min(max(x0i, 0), W_ - 1), cx1 = min(max(x1, 0), W_ - 1);
            wgt[pl][k] = make_float4(mk * (1.f - ty) * (1.f - tx) * vy0 * vx0,
                                     mk * (1.f - ty) * tx         * vy0 * vx1,
                                     mk * ty         * (1.f - tx) * vy1 * vx0,
                                     mk * ty         * tx         * vy1 * vx1);
            soff[pl][k] = make_uint4((unsigned)((cy0 * W_ + cx0) << 9),
                                     (unsigned)((cy0 * W_ + cx1) << 9),
                                     (unsigned)((cy1 * W_ + cx0) << 9),
                                     (unsigned)((cy1 * W_ + cx1) << 9));
        }
        __syncthreads();
        // --- gather for this chunk ---
        const int p = rep * 8 + (lp >> 3);
        float acc[8] = {0.f, 0.f, 0.f, 0.f, 0.f, 0.f, 0.f, 0.f};
#pragma unroll
        for (int k = 0; k < K_; k++) {
            float4 wk = wgt[lp][k];
            uint4  ok = soff[lp][k];
            const uint4 v00 = *(const uint4*)(vb + ok.x);
            const uint4 v01 = *(const uint4*)(vb + ok.y);
            const uint4 v10 = *(const uint4*)(vb + ok.z);
            const uint4 v11 = *(const uint4*)(vb + ok.w);
#define ACC8(V, WW) { \
            acc[0] += WW * bflo(V.x); acc[1] += WW * bfhi(V.x); \
            acc[2] += WW * bflo(V.y); acc[3] += WW * bfhi(V.y); \
            acc[4] += WW * bflo(V.z); acc[5] += WW * bfhi(V.z); \
            acc[6] += WW * bflo(V.w); acc[7] += WW * bfhi(V.w); }
            ACC8(v00, wk.x) ACC8(v01, wk.y) ACC8(v10, wk.z) ACC8(v11, wk.w)
#undef ACC8
        }
        uint4 pk;
        unsigned short* ps = (unsigned short*)&pk;
#pragma unroll
        for (int i = 0; i < 8; i++) ps[i] = f2bf(acc[i]);
        int phys = slot ^ (p & 7);
        *(uint4*)&interm[p * 256 + phys * 8] = pk;
    }
    __syncthreads();

    // --- Phase C: per wave 64q x 64px, 4x4 frags, K=256 in 8 steps ---
    const int wave = tid >> 6, lane = tid & 63;
    const int lm = lane & 15, kq = lane >> 4;
    const int q0w = wave * 64;
    frag_cd acc2[4][4];
#pragma unroll
    for (int a = 0; a < 4; a++)
#pragma unroll
        for (int c = 0; c < 4; c++) acc2[a][c] = (frag_cd){0.f, 0.f, 0.f, 0.f};

    for (int k0 = 0; k0 < C_; k0 += 32) {
        frag_ab af[4], bfr[4];
#pragma unroll
        for (int mi = 0; mi < 4; mi++)
            af[mi] = *(const frag_ab*)(opw + (size_t)(q0w + mi * 16 + lm) * C_ + k0 + kq * 8);
#pragma unroll
        for (int ni = 0; ni < 4; ni++) {
            int pxr = ni * 16 + lm;
            int phys = (k0 / 8 + kq) ^ (pxr & 7);
            bfr[ni] = *(const frag_ab*)&interm[pxr * 256 + phys * 8];
        }
#pragma unroll
        for (int mi = 0; mi < 4; mi++)
#pragma unroll
            for (int ni = 0; ni < 4; ni++)
                acc2[mi][ni] = __builtin_amdgcn_mfma_f32_16x16x32_bf16(af[mi], bfr[ni], acc2[mi][ni], 0, 0, 0);
    }

    float* ob = out + (size_t)n * C_ * L_ + l0;
#pragma unroll
    for (int mi = 0; mi < 4; mi++) {
#pragma unroll
        for (int ni = 0; ni < 4; ni++) {
            int pxr = ni * 16 + lm;
#pragma unroll
            for (int r = 0; r < 4; r++) {
                int q = q0w + mi * 16 + kq * 4 + r;
                ob[(size_t)q * L_ + pxr] = acc2[mi][ni][r];
            }
        }
    }
}

// ---------------------------------------------------------------------------
// Workspace layout (84,280,320 B total):
//   [0,        16777216)  xb (n,L,C) bf16
//   [16777216, 33554432)  omb (n,L,C) bf16
//   [33554432, 50331648)  valueb (n,L,C) bf16
//   [50331648, 83886080)  omf (n,L,256) fp32
//   [83886080, ...)       vp_wb, om_wb, op_wb bf16 (128KB each), om_bp fp32
// ---------------------------------------------------------------------------
extern "C" void kernel_launch(void* const* d_in, const int* in_sizes, int n_in,
                              void* d_out, int out_size, void* d_ws, size_t ws_size,
                              hipStream_t stream) {
    const float* x    = (const float*)d_in[0];
    const float* dw_w = (const float*)d_in[1];
    const float* dw_b = (const float*)d_in[2];
    const float* om_w = (const float*)d_in[3];
    const float* om_b = (const float*)d_in[4];
    const float* vp_w = (const float*)d_in[5];
    const float* vp_b = (const float*)d_in[6];
    const float* op_w = (const float*)d_in[7];
    float* out = (float*)d_out;

    char* ws = (char*)d_ws;
    unsigned short* xb      = (unsigned short*)(ws);
    unsigned short* omb     = (unsigned short*)(ws + 16777216);
    unsigned short* valueb  = (unsigned short*)(ws + 33554432);
    float*          omf     = (float*)(ws + 50331648);
    unsigned short* vp_wb   = (unsigned short*)(ws + 83886080);
    unsigned short* om_wb   = (unsigned short*)(ws + 84017152);
    unsigned short* op_wb   = (unsigned short*)(ws + 84148224);
    float*          om_bp   = (float*)(ws + 84279296);

    // 1) fused depthwise conv + x transpose + weight conversion
    prep_kernel<<<dim3(C_ / 32, H_, N_), 256, 0, stream>>>(
        x, dw_w, dw_b, vp_w, om_w, om_b, op_w,
        xb, omb, vp_wb, om_wb, om_bp, op_wb);
    // 2) value = xb @ vp_w^T + vp_b  AND  om = omb @ om_w^T + om_b
    gemm12_kernel<<<dim3(256, 2, 2), 256, 0, stream>>>(
        xb, omb, vp_wb, om_wb, vp_b, om_bp, valueb, omf);
    // 3) fused sampling + output projection -> out (NCHW fp32)
    samplegemm_kernel<<<dim3(L_ / 64, N_), 256, 0, stream>>>(valueb, omf, op_wb, out);
}